// Round 2
// baseline (3138.224 us; speedup 1.0000x reference)
//
#include <hip/hip_runtime.h>
#include <math.h>

#define NN 100000
#define EE 2000000
#define DD 32
#define LL 6
#define RR 50
#define BB 64

// ---------------- workspace layout (bytes) ----------------
// cnt:    int[N]        @ 0
// wdeg:   float[N]      @ 400000
// rowptr: int[N+1]      @ 800000   (400016 reserved)
// cursor: int[N]        @ 1200016
// scale:  float[N]      @ 1600016
// iscale: float[N]      @ 2000016
// bnd:    float[N]      @ 2400016
// logsum: double        @ 2800016  (pad to 2800032)
// recs:   int4[E]       @ 2800032  (32,000,000)
// xbuf0:  float[N*32]   @ 34800032 (12,800,000)
// xbuf1:  float[N*32]   @ 47600032 (12,800,000)
// total ~60.4 MB

__global__ void hist_kernel(const int* __restrict__ ei, const float* __restrict__ ew,
                            int* __restrict__ cnt, float* __restrict__ wdeg) {
    for (int e = blockIdx.x * blockDim.x + threadIdx.x; e < EE; e += gridDim.x * blockDim.x) {
        int nout = ei[2 * e + 1];
        atomicAdd(&cnt[nout], 1);
        atomicAdd(&wdeg[nout], ew[e]);
    }
}

__global__ void boundary_kernel(const int* __restrict__ h, float* __restrict__ bnd,
                                float* __restrict__ x0) {
    int t = blockIdx.x * blockDim.x + threadIdx.x;  // 0..B*32-1
    if (t >= BB * DD) return;
    int bidx = t >> 5, d = t & 31;
    int node = h[bidx];
    x0[node * DD + d] = 1.0f;
    if (d == 0) bnd[node] = 1.0f;
}

__global__ void scan_kernel(const int* __restrict__ cnt, int* __restrict__ rowptr,
                            int* __restrict__ cursor) {
    __shared__ int sh[1024];
    int carry = 0;
    for (int base = 0; base < NN; base += 1024) {
        int i = base + (int)threadIdx.x;
        int v = (i < NN) ? cnt[i] : 0;
        sh[threadIdx.x] = v;
        __syncthreads();
        for (int off = 1; off < 1024; off <<= 1) {
            int t = (threadIdx.x >= (unsigned)off) ? sh[threadIdx.x - off] : 0;
            __syncthreads();
            sh[threadIdx.x] += t;
            __syncthreads();
        }
        int excl = sh[threadIdx.x] - v + carry;
        if (i < NN) { rowptr[i] = excl; cursor[i] = excl; }
        carry += sh[1023];
        __syncthreads();
    }
    if (threadIdx.x == 0) rowptr[NN] = carry;
}

__global__ void logsum_kernel(const float* __restrict__ wdeg, double* __restrict__ out) {
    __shared__ double sh[256];
    double local = 0.0;
    for (int i = blockIdx.x * blockDim.x + threadIdx.x; i < NN; i += gridDim.x * blockDim.x)
        local += log((double)wdeg[i] + 1.0);
    sh[threadIdx.x] = local;
    __syncthreads();
    for (int o = 128; o > 0; o >>= 1) {
        if (threadIdx.x < (unsigned)o) sh[threadIdx.x] += sh[threadIdx.x + o];
        __syncthreads();
    }
    if (threadIdx.x == 0) atomicAdd(out, sh[0]);
}

__global__ void scalefin_kernel(const float* __restrict__ wdeg, const double* __restrict__ logsum,
                                float* __restrict__ scalev, float* __restrict__ iscalev) {
    float mean = (float)(logsum[0] / (double)NN);
    for (int i = blockIdx.x * blockDim.x + threadIdx.x; i < NN; i += gridDim.x * blockDim.x) {
        float s = logf(wdeg[i] + 1.0f) / mean;
        scalev[i] = s;
        iscalev[i] = 1.0f / fmaxf(s, 0.01f);
    }
}

__global__ void scatter_kernel(const int* __restrict__ ei, const int* __restrict__ et,
                               const float* __restrict__ ew, int* __restrict__ cursor,
                               int4* __restrict__ recs) {
    for (int e = blockIdx.x * blockDim.x + threadIdx.x; e < EE; e += gridDim.x * blockDim.x) {
        int nin = ei[2 * e];
        int nout = ei[2 * e + 1];
        int pos = atomicAdd(&cursor[nout], 1);
        recs[pos] = make_int4(nin, et[e], __float_as_int(ew[e]), 0);
    }
}

// One wave (64 lanes) per node. Lanes 0-31 & 32-63 each take one edge per
// iteration over the 32 feature dims; halves combined with shfl_xor(32).
// Fused epilogue: feat/scales + 416x32 matmul via shfl broadcast vs W in LDS.
__global__ __launch_bounds__(256, 2) void layer_kernel(
    const float* __restrict__ xin, float* __restrict__ xout,
    const int4* __restrict__ recs, const int* __restrict__ rowptr,
    const float* __restrict__ bnd, const float* __restrict__ scalev,
    const float* __restrict__ iscalev,
    const float* __restrict__ Wl, const float* __restrict__ bl,
    const float* __restrict__ rel_l) {
    __shared__ float W_s[416 * 32];   // 53248 B
    __shared__ float rel_s[RR * 32];  // 6400 B
    __shared__ float b_s[32];

    {
        const float4* w4 = (const float4*)Wl;
        float4* ws4 = (float4*)W_s;
        for (int i = threadIdx.x; i < (416 * 32) / 4; i += 256) ws4[i] = w4[i];
        const float4* r4 = (const float4*)rel_l;
        float4* rs4 = (float4*)rel_s;
        for (int i = threadIdx.x; i < (RR * 32) / 4; i += 256) rs4[i] = r4[i];
        if (threadIdx.x < 32) b_s[threadIdx.x] = bl[threadIdx.x];
    }
    __syncthreads();

    const int lane = threadIdx.x & 63;
    const int half = lane >> 5;
    const int d = lane & 31;  // feature dim for aggregation; output col for matmul
    const int wid = blockIdx.x * 4 + (threadIdx.x >> 6);
    const int nwaves = gridDim.x * 4;

    for (int n = wid; n < NN; n += nwaves) {
        const int row = rowptr[n];
        const int end = rowptr[n + 1];
        const float bv = bnd[n];
        // Boundary self-entry (w=1) must be counted exactly ONCE in the
        // sums (halves are added via shfl_xor), but max/min are idempotent.
        float s = (half == 0) ? bv : 0.0f;
        float ssq = s;  // bv*bv == bv (bv in {0,1})
        float mx = bv, mn = bv;

        for (int e = row + half; e < end; e += 2) {
            const int4 r = recs[e];
            const float w = __int_as_float(r.z);
            const float msg = xin[r.x * DD + d] * rel_s[r.y * DD + d];
            const float mw = msg * w;
            s += mw;
            ssq = fmaf(mw, msg, ssq);
            mx = fmaxf(mx, mw);
            mn = fminf(mn, mw);
        }
        s += __shfl_xor(s, 32);
        ssq += __shfl_xor(ssq, 32);
        mx = fmaxf(mx, __shfl_xor(mx, 32));
        mn = fminf(mn, __shfl_xor(mn, 32));

        const float cntn = (float)(end - row + 1);
        const float inv = 1.0f / cntn;
        const float mean = s * inv;
        const float sqm = ssq * inv;
        const float var = sqm - mean * mean;
        const float stdv = sqrtf(fmaxf(var, 1e-6f));
        const float scl = scalev[n];
        const float iscl = iscalev[n];

        float vals[13];
        vals[0] = xin[n * DD + d];
        const float f[4] = {mean, mx, mn, stdv};
#pragma unroll
        for (int k = 0; k < 4; k++) {
            vals[1 + k * 3 + 0] = f[k];
            vals[1 + k * 3 + 1] = f[k] * scl;
            vals[1 + k * 3 + 2] = f[k] * iscl;
        }

        // matmul: out[j] = sum_i in[i] * W[i][j], j = d. Lower half sums input
        // dims 0..15 (from lanes 0..15), upper half dims 16..31 (lanes 48..63).
        float acc = 0.0f;
        const int srcBase = half * 48;
#pragma unroll
        for (int t = 0; t < 16; t++) {
            const int src = srcBase + t;
            const int deff = half * 16 + t;
            float v0 = __shfl(vals[0], src);
            acc = fmaf(v0, W_s[deff * 32 + d], acc);
            const float* wr = &W_s[(32 + deff * 12) * 32 + d];
#pragma unroll
            for (int c = 0; c < 12; c++) {
                float v = __shfl(vals[1 + c], src);
                acc = fmaf(v, wr[c * 32], acc);
            }
        }
        acc += __shfl_xor(acc, 32);
        const float o = fmaxf(acc + b_s[d], 0.0f);
        if (half == 0) xout[n * DD + d] = o;
    }
}

extern "C" void kernel_launch(void* const* d_in, const int* in_sizes, int n_in,
                              void* d_out, int out_size, void* d_ws, size_t ws_size,
                              hipStream_t stream) {
    const int* ei = (const int*)d_in[0];
    const int* et = (const int*)d_in[1];
    const float* ew = (const float*)d_in[2];
    const int* hidx = (const int*)d_in[3];
    const float* rel = (const float*)d_in[4];
    const float* W = (const float*)d_in[5];
    const float* b = (const float*)d_in[6];

    char* ws = (char*)d_ws;
    int* cnt = (int*)(ws + 0);
    float* wdeg = (float*)(ws + 400000);
    int* rowptr = (int*)(ws + 800000);
    int* cursor = (int*)(ws + 1200016);
    float* scalev = (float*)(ws + 1600016);
    float* iscalev = (float*)(ws + 2000016);
    float* bnd = (float*)(ws + 2400016);
    double* logsum = (double*)(ws + 2800016);
    int4* recs = (int4*)(ws + 2800032);
    float* xbuf0 = (float*)(ws + 34800032);
    float* xbuf1 = (float*)(ws + 47600032);

    // zero: cnt, wdeg, bnd, logsum (and harmlessly rowptr/cursor/scales), x0
    hipMemsetAsync(ws, 0, 2800032, stream);
    hipMemsetAsync(xbuf0, 0, NN * DD * sizeof(float), stream);

    hist_kernel<<<1024, 256, 0, stream>>>(ei, ew, cnt, wdeg);
    boundary_kernel<<<(BB * DD + 255) / 256, 256, 0, stream>>>(hidx, bnd, xbuf0);
    scan_kernel<<<1, 1024, 0, stream>>>(cnt, rowptr, cursor);
    logsum_kernel<<<256, 256, 0, stream>>>(wdeg, logsum);
    scalefin_kernel<<<400, 256, 0, stream>>>(wdeg, logsum, scalev, iscalev);
    scatter_kernel<<<1024, 256, 0, stream>>>(ei, et, ew, cursor, recs);

    float* xout_final = (float*)d_out;
    for (int l = 0; l < LL; l++) {
        const float* xin = (l % 2 == 0) ? xbuf0 : xbuf1;
        float* xout = (l == LL - 1) ? xout_final : ((l % 2 == 0) ? xbuf1 : xbuf0);
        layer_kernel<<<512, 256, 0, stream>>>(
            xin, xout, recs, rowptr, bnd, scalev, iscalev,
            W + (size_t)l * 416 * 32, b + (size_t)l * 32, rel + (size_t)l * RR * 32);
    }
}